// Round 8
// baseline (402.353 us; speedup 1.0000x reference)
//
#include <hip/hip_runtime.h>
#include <math.h>

#define B    32
#define S    2048
#define NP   8
#define NSL  32     // hid-slices (16 hid each)
#define HSL  16
#define BG   4      // batches per group, 8 groups
#define NCH  8      // attn chunks per batch
#define SCHUNK 256
#define NBLK 256    // == #CUs -> guaranteed co-residency at 1 block/CU
#define NTHR 512
#define NBAR 16     // 2 barriers/step * 8 steps

// Cross-block mutable data goes through the coherence point (sc1) with NO
// cache-maintenance: relaxed agent-scope atomics. Read-only bulk (enc, Wt,
// Wq, biases) stays on the normal cached path -> L2 stays warm all kernel.
#define AT_LD(p)   __hip_atomic_load((p), __ATOMIC_RELAXED, __HIP_MEMORY_SCOPE_AGENT)
#define AT_ST(p,v) __hip_atomic_store((p), (v), __ATOMIC_RELAXED, __HIP_MEMORY_SCOPE_AGENT)

__device__ __forceinline__ float sigmoidf_(float x) {
  return 1.0f / (1.0f + __expf(-x));
}

// Fence-free grid barrier: per-wave vmcnt(0) (sc1 stores are acked at the
// coherence point), relaxed arrival RMW (nothing dirty to flush -- all
// cross-block stores were write-through), relaxed spin, no exit fence
// (consumers re-read via sc1 loads; cached reads are immutable data only).
__device__ __forceinline__ void gbar(int* cnt, int bi) {
  asm volatile("s_waitcnt vmcnt(0) lgkmcnt(0)" ::: "memory");
  __syncthreads();
  if (threadIdx.x == 0) {
    int* base = cnt + bi * 128;
    __hip_atomic_fetch_add(base + (blockIdx.x & 7) * 16, 1,
                           __ATOMIC_RELAXED, __HIP_MEMORY_SCOPE_AGENT);
    int s;
    do {
      s = 0;
      #pragma unroll
      for (int q = 0; q < 8; ++q) s += AT_LD(base + q * 16);
      if (s < NBLK) __builtin_amdgcn_s_sleep(2);
    } while (s < NBLK);
  }
  __syncthreads();
  asm volatile("" ::: "memory");
}

// ---------------- init: Wt = [W_ih | W_hh]^T, h0/xin0 broadcast, ns, counters ----------------
__global__ __launch_bounds__(256)
void k_init(const float* __restrict__ W_ih, const float* __restrict__ W_hh,
            const float* __restrict__ init_h, const float* __restrict__ init_in,
            const int* __restrict__ ns_raw,
            float* __restrict__ Wt, float* __restrict__ hbuf,
            float* __restrict__ xin0, int* __restrict__ ns, int* __restrict__ cnt) {
  __shared__ float tbuf[64][65];
  const int blk = blockIdx.x, tid = threadIdx.x;
  const int jt = blk & 31, kt = blk >> 5;        // 32 j-tiles x 16 k-tiles of 64x64
  const int j0 = jt * 64, k0 = kt * 64;
  const int r0 = tid >> 6, cc = tid & 63;
  for (int rr = r0; rr < 64; rr += 4) {
    int j = j0 + rr, k = k0 + cc;
    tbuf[rr][cc] = (k < 512) ? W_ih[(size_t)j * 512 + k]
                             : W_hh[(size_t)j * 512 + (k - 512)];
  }
  __syncthreads();
  for (int rr = r0; rr < 64; rr += 4)
    Wt[(size_t)(k0 + rr) * 2048 + j0 + cc] = tbuf[cc][rr];

  int idx = blk * 256 + tid;
  if (idx < B * 512) {
    int d = idx & 511;
    hbuf[idx] = init_h[d];        // slot 0 = h(-1)
    xin0[idx] = init_in[d];
  }
  if (idx < NBAR * 128) cnt[idx] = 0;   // re-zeroed every call -> replay-safe
  if (idx == 0) {
    // num_sent >= 1 always. If int64 (LE), high word of elem 0 (raw[1]) is 0.
    bool is64 = (ns_raw[1] == 0);
    for (int i = 0; i < B; ++i) ns[i] = is64 ? ns_raw[2 * i] : ns_raw[i];
  }
}

// ---------------- single persistent kernel, 256 blocks x 512 threads ----------------
// step t: [reduce(t-1)->X,score | gates | cell | qpart]  gbar  [qsum | attn]  gbar
__global__ __launch_bounds__(NTHR, 1)
void k_persist(const float* __restrict__ enc, const float* __restrict__ init_c,
               const float* __restrict__ bih, const float* __restrict__ bhh,
               const float* __restrict__ Wq, const float* __restrict__ scW,
               const float* __restrict__ scb, const float* __restrict__ Wt,
               const float* __restrict__ xin0,
               float* __restrict__ out, float* __restrict__ hbuf,
               float* __restrict__ qpart, float* __restrict__ ch_m,
               float* __restrict__ ch_l, float* __restrict__ ch_o,
               const int* __restrict__ ns, int* __restrict__ cnt) {
  __shared__ float X[BG][1024];        // 16 KB  [xin | h(t-1)]
  __shared__ float gacc[8][64][5];     // 10 KB  (pad 5: 2-way banks on reduce)
  __shared__ float gl[4][HSL][BG];
  __shared__ float hl[BG][HSL];
  __shared__ float sred[8][BG];
  __shared__ float q_lds[512];
  __shared__ float wm[8], wl[8];
  __shared__ float wo[8][512];         // 16 KB

  const int tid = threadIdx.x;
  const int blk = blockIdx.x;
  const int sl  = blk >> 3;            // step phase: hid slice
  const int bg  = blk & 7;             // step phase: batch group
  const int b0  = bg * BG;
  const int ab  = blk >> 3;            // attn phase: batch
  const int ach = blk & 7;             // attn phase: chunk
  const int lane = tid & 63;
  const int wv = tid >> 6;

  // hoisted per-block constants
  float wq[HSL];
  #pragma unroll
  for (int ho = 0; ho < HSL; ++ho)
    wq[ho] = Wq[(size_t)(sl * HSL + ho) * 512 + tid];
  const float swd = scW[tid];
  const float scb0 = scb[0];
  float c_reg = (tid < BG * HSL) ? init_c[sl * HSL + (tid & (HSL - 1))] : 0.f;
  const int nsb = ns[ab];
  const size_t rowbase = (size_t)ab * S;

  for (int t = 0; t < NP; ++t) {
    // ======== phase 1 ========
    if (t == 0) {
      #pragma unroll
      for (int bl = 0; bl < BG; ++bl)
        X[bl][tid] = xin0[(b0 + bl) * 512 + tid];
    } else {
      #pragma unroll
      for (int bl = 0; bl < BG; ++bl) {
        const int b = b0 + bl;
        float M = -1e30f;
        #pragma unroll
        for (int c = 0; c < NCH; ++c) M = fmaxf(M, AT_LD(&ch_m[b * NCH + c]));
        float e[NCH]; float L = 0.f;
        #pragma unroll
        for (int c = 0; c < NCH; ++c) {
          e[c] = __expf(AT_LD(&ch_m[b * NCH + c]) - M);
          L += AT_LD(&ch_l[b * NCH + c]) * e[c];
        }
        float v = 0.f;
        #pragma unroll
        for (int c = 0; c < NCH; ++c)
          v += AT_LD(&ch_o[((size_t)(b * NCH + c)) * 512 + tid]) * e[c];
        v *= (1.0f / L);
        X[bl][tid] = v;
        float p = v * swd;
        #pragma unroll
        for (int off = 32; off > 0; off >>= 1) p += __shfl_xor(p, off);
        if (lane == 0) sred[wv][bl] = p;
      }
    }
    {
      const float* hsrc = hbuf + (t & 1) * (B * 512);
      #pragma unroll
      for (int i = 0; i < 4; ++i) {
        int idx = i * 512 + tid;
        int bl = idx >> 9, off = idx & 511;
        X[bl][512 + off] = AT_LD(&hsrc[(b0 + bl) * 512 + off]);
      }
    }
    __syncthreads();
    if (t >= 1 && sl == 0 && tid < BG) {
      float s = 0.f;
      #pragma unroll
      for (int w = 0; w < 8; ++w) s += sred[w][tid];
      out[(t - 1) * B + b0 + tid] = s + scb0;
    }

    // gates: jloc = (gi,ho) per lane, kc = wave; full-K split over 8 waves
    {
      const int jloc = tid & 63, kc = tid >> 6;
      const int gi = jloc >> 4, ho = jloc & 15;
      const int jg = gi * 512 + sl * HSL + ho;
      const float* wp = Wt + (size_t)(kc * 128) * 2048 + jg;
      const int xk0 = kc * 128;
      float a0 = 0, a1 = 0, a2 = 0, a3 = 0;
      #pragma unroll 4
      for (int kk = 0; kk < 32; ++kk) {
        float w0 = wp[(size_t)(kk * 4 + 0) * 2048];
        float w1 = wp[(size_t)(kk * 4 + 1) * 2048];
        float w2 = wp[(size_t)(kk * 4 + 2) * 2048];
        float w3 = wp[(size_t)(kk * 4 + 3) * 2048];
        float4 x0 = *(const float4*)&X[0][xk0 + kk * 4];
        float4 x1 = *(const float4*)&X[1][xk0 + kk * 4];
        float4 x2 = *(const float4*)&X[2][xk0 + kk * 4];
        float4 x3 = *(const float4*)&X[3][xk0 + kk * 4];
        a0 += w0 * x0.x + w1 * x0.y + w2 * x0.z + w3 * x0.w;
        a1 += w0 * x1.x + w1 * x1.y + w2 * x1.z + w3 * x1.w;
        a2 += w0 * x2.x + w1 * x2.y + w2 * x2.z + w3 * x2.w;
        a3 += w0 * x3.x + w1 * x3.y + w2 * x3.z + w3 * x3.w;
      }
      gacc[kc][jloc][0] = a0; gacc[kc][jloc][1] = a1;
      gacc[kc][jloc][2] = a2; gacc[kc][jloc][3] = a3;
    }
    __syncthreads();

    if (tid < 256) {
      const int jloc = tid & 63, bl = tid >> 6;
      const int gi = jloc >> 4, ho = jloc & 15;
      const int jg = gi * 512 + sl * HSL + ho;
      float g = bih[jg] + bhh[jg];
      #pragma unroll
      for (int kc = 0; kc < 8; ++kc) g += gacc[kc][jloc][bl];
      gl[gi][ho][bl] = g;
    }
    __syncthreads();
    if (tid < BG * HSL) {                        // 64 owners of (bl,ho)
      const int bl = tid >> 4, ho = tid & 15;
      float i_ = sigmoidf_(gl[0][ho][bl]);
      float f_ = sigmoidf_(gl[1][ho][bl]);
      float g_ = tanhf(gl[2][ho][bl]);
      float o_ = sigmoidf_(gl[3][ho][bl]);
      float cn = f_ * c_reg + i_ * g_;
      c_reg = cn;                                // c lives in registers across steps
      float hv = o_ * tanhf(cn);
      hl[bl][ho] = hv;
      AT_ST(&hbuf[((t + 1) & 1) * (B * 512) + (b0 + bl) * 512 + sl * HSL + ho], hv);
    }
    __syncthreads();
    #pragma unroll
    for (int bl = 0; bl < BG; ++bl) {
      float acc = 0.f;
      #pragma unroll
      for (int ho = 0; ho < HSL; ++ho) acc += hl[bl][ho] * wq[ho];
      AT_ST(&qpart[((size_t)sl * B + b0 + bl) * 512 + tid], acc);
    }
    gbar(cnt, t * 2 + 0);

    // ======== phase 2: attn ========
    {
      float s = 0.f;
      #pragma unroll 8
      for (int s2 = 0; s2 < NSL; ++s2)
        s += AT_LD(&qpart[((size_t)s2 * B + ab) * 512 + tid]);
      q_lds[tid] = s;
    }
    __syncthreads();

    {
      const float4 qa  = *(const float4*)&q_lds[lane * 8];
      const float4 qb4 = *(const float4*)&q_lds[lane * 8 + 4];
      const int s0 = ach * SCHUNK;
      float m = -1e30f, l = 0.f;
      float o0=0,o1=0,o2=0,o3=0,o4=0,o5=0,o6=0,o7=0;
      const int send = min(s0 + SCHUNK, nsb);

      int r = s0 + 2 * wv;
      if (r < send) {
        bool has1 = (r + 1 < send);
        const float4* p0 = (const float4*)(enc + (rowbase + r) * 512 + lane * 8);
        const float4* p1 = (const float4*)(enc + (rowbase + (has1 ? r + 1 : r)) * 512 + lane * 8);
        float4 a0 = p0[0], a1 = p0[1];
        float4 c0 = p1[0], c1 = p1[1];
        while (true) {
          const int rn = r + 16;
          const bool hasn = (rn < send);
          float4 na0, na1, nc0, nc1;
          bool nhas1 = false;
          if (hasn) {
            nhas1 = (rn + 1 < send);
            const float4* f0 = (const float4*)(enc + (rowbase + rn) * 512 + lane * 8);
            const float4* f1 = (const float4*)(enc + (rowbase + (nhas1 ? rn + 1 : rn)) * 512 + lane * 8);
            na0 = f0[0]; na1 = f0[1]; nc0 = f1[0]; nc1 = f1[1];
          }
          float d0 = qa.x*a0.x + qa.y*a0.y + qa.z*a0.z + qa.w*a0.w
                   + qb4.x*a1.x + qb4.y*a1.y + qb4.z*a1.z + qb4.w*a1.w;
          float d1 = qa.x*c0.x + qa.y*c0.y + qa.z*c0.z + qa.w*c0.w
                   + qb4.x*c1.x + qb4.y*c1.y + qb4.z*c1.z + qb4.w*c1.w;
          #pragma unroll
          for (int off = 32; off > 0; off >>= 1) {
            d0 += __shfl_xor(d0, off);
            d1 += __shfl_xor(d1, off);
          }
          if (!has1) d1 = -1e30f;            // wave-uniform
          float nm = fmaxf(m, fmaxf(d0, d1));
          float sc = __expf(m - nm);
          float w0 = __expf(d0 - nm);
          float w1 = __expf(d1 - nm);
          l = l * sc + w0 + w1;
          o0 = o0*sc + w0*a0.x + w1*c0.x; o1 = o1*sc + w0*a0.y + w1*c0.y;
          o2 = o2*sc + w0*a0.z + w1*c0.z; o3 = o3*sc + w0*a0.w + w1*c0.w;
          o4 = o4*sc + w0*a1.x + w1*c1.x; o5 = o5*sc + w0*a1.y + w1*c1.y;
          o6 = o6*sc + w0*a1.z + w1*c1.z; o7 = o7*sc + w0*a1.w + w1*c1.w;
          m = nm;
          if (!hasn) break;
          r = rn; has1 = nhas1;
          a0 = na0; a1 = na1; c0 = nc0; c1 = nc1;
        }
      }
      if (lane == 0) { wm[wv] = m; wl[wv] = l; }
      float4* wop = (float4*)&wo[wv][lane * 8];
      wop[0] = make_float4(o0, o1, o2, o3);
      wop[1] = make_float4(o4, o5, o6, o7);
      __syncthreads();

      float M = wm[0];
      #pragma unroll
      for (int w = 1; w < 8; ++w) M = fmaxf(M, wm[w]);
      float e[8]; float L = 0.f;
      #pragma unroll
      for (int w = 0; w < 8; ++w) { e[w] = __expf(wm[w] - M); L += wl[w] * e[w]; }
      if (tid == 0) {
        AT_ST(&ch_m[ab * NCH + ach], M);
        AT_ST(&ch_l[ab * NCH + ach], L);
      }
      float v = 0.f;
      #pragma unroll
      for (int w = 0; w < 8; ++w) v += wo[w][tid] * e[w];
      AT_ST(&ch_o[((size_t)(ab * NCH + ach)) * 512 + tid], v);
    }
    gbar(cnt, t * 2 + 1);
  }

  // ======== final score (t = NP) ========
  if (blk < 8) {
    const int fb0 = blk * BG;
    #pragma unroll
    for (int bl = 0; bl < BG; ++bl) {
      const int b = fb0 + bl;
      float M = -1e30f;
      #pragma unroll
      for (int c = 0; c < NCH; ++c) M = fmaxf(M, AT_LD(&ch_m[b * NCH + c]));
      float e[NCH]; float L = 0.f;
      #pragma unroll
      for (int c = 0; c < NCH; ++c) {
        e[c] = __expf(AT_LD(&ch_m[b * NCH + c]) - M);
        L += AT_LD(&ch_l[b * NCH + c]) * e[c];
      }
      float v = 0.f;
      #pragma unroll
      for (int c = 0; c < NCH; ++c)
        v += AT_LD(&ch_o[((size_t)(b * NCH + c)) * 512 + tid]) * e[c];
      v *= (1.0f / L);
      float p = v * swd;
      #pragma unroll
      for (int off = 32; off > 0; off >>= 1) p += __shfl_xor(p, off);
      if (lane == 0) sred[wv][bl] = p;
    }
    __syncthreads();
    if (tid < BG) {
      float s = 0.f;
      #pragma unroll
      for (int w = 0; w < 8; ++w) s += sred[w][tid];
      out[(NP - 1) * B + fb0 + tid] = s + scb0;
    }
  }
}

extern "C" void kernel_launch(void* const* d_in, const int* in_sizes, int n_in,
                              void* d_out, int out_size, void* d_ws, size_t ws_size,
                              hipStream_t stream) {
  const float* enc     = (const float*)d_in[0];
  const int*   ns_raw  = (const int*)d_in[1];
  // d_in[2] = num_pred (8)
  const float* init_h  = (const float*)d_in[3];
  const float* init_c  = (const float*)d_in[4];
  const float* init_in = (const float*)d_in[5];
  const float* W_ih    = (const float*)d_in[6];
  const float* W_hh    = (const float*)d_in[7];
  const float* b_ih    = (const float*)d_in[8];
  const float* b_hh    = (const float*)d_in[9];
  const float* Wq      = (const float*)d_in[10];
  const float* score_W = (const float*)d_in[11];
  const float* score_b = (const float*)d_in[12];
  float* out = (float*)d_out;

  float* ws    = (float*)d_ws;
  float* Wt    = ws;                   // 2097152
  float* hbuf  = ws + 2097152;         // 2*B*512 = 32768 (double-buffered)
  float* xin0  = ws + 2129920;         // 16384
  float* qpart = ws + 2146304;         // 32*32*512 = 524288
  float* ch_m  = ws + 2670592;         // 256
  float* ch_l  = ws + 2670848;         // 256
  float* ch_o  = ws + 2671104;         // 32*8*512 = 131072
  int*   ns    = (int*)(ws + 2802176); // 32 ints
  int*   cnt   = (int*)(ws + 2802208); // NBAR*128 = 2048 ints

  k_init<<<512, 256, 0, stream>>>(W_ih, W_hh, init_h, init_in, ns_raw,
                                  Wt, hbuf, xin0, ns, cnt);
  k_persist<<<NBLK, NTHR, 0, stream>>>(enc, init_c, b_ih, b_hh, Wq, score_W, score_b,
                                       Wt, xin0, out, hbuf, qpart,
                                       ch_m, ch_l, ch_o, ns, cnt);
}